// Round 1
// 93.754 us; speedup vs baseline: 1.1069x; 1.1069x over previous
//
#include <hip/hip_runtime.h>
#include <cstdint>
#include <cstddef>

#define NPTS 8192
#define NUM_CLASSES 5
#define XCOLS 10          // 3 coords + batch + feat + 5 seg
#define EPS2 225.0f
#define MIN_PTS 5
#define NGROUPS 10
#define BIGC 0x3fffffff

#define NLCAP 1536        // max nodes per group (expect ~820)
#define EACAP 8192        // per-group eps-pairs u<v (expect ~5.4k)
#define ELCAP 8192        // core-core edges
#define EBCAP 2048        // core-noncore edges (expect ~500)
#define CPAD 64           // per-group edge counters padded 256 B apart
#define NSLICE 16         // row slices per group in k_pairs (was 8)
#define NRPS (NLCAP / NSLICE)   // 96 rows per slice
#define ROUNDS 16

// ---------------- prep: fused setup+nodes ------------------------------------
// One block per group. Each block redundantly computes every point's group
// (argmax over seg + batch), builds the ordered per-group node list via
// ballot+prefix, and writes a PACKED per-group float4 coord array qg so
// k_pairs' LDS fill is a coalesced streaming copy (no gather).
__global__ void __launch_bounds__(1024) k_prep(
        const float* __restrict__ x, float4* __restrict__ qg,
        int* __restrict__ nlist_g, int* __restrict__ nn_g,
        unsigned int* __restrict__ gcnt) {
    __shared__ unsigned long long masks[NPTS / 64];   // 128 words
    __shared__ int pref[NPTS / 64];
    __shared__ int nnS;
    const int g = blockIdx.x;
    const int tid = threadIdx.x, lane = tid & 63, wv = tid >> 6;

    if (tid < CPAD) gcnt[g * CPAD + tid] = 0u;        // zero my group's counters

    for (int w = wv; w < NPTS / 64; w += 16) {
        int i = w * 64 + lane;
        const float* r = x + (size_t)i * XCOLS;
        int b = (int)r[3];
        float best = r[5]; int bc = 0;
        #pragma unroll
        for (int c = 1; c < NUM_CLASSES; c++) {
            float v = r[5 + c];
            if (v > best) { best = v; bc = c; }       // strict > keeps first max
        }
        unsigned long long bm = __ballot(b * NUM_CLASSES + bc == g);
        if (lane == 0) masks[w] = bm;
    }
    __syncthreads();
    if (wv == 0) {                         // 2-chunk scan of 128 popcounts
        int v0 = __popcll(masks[lane]);
        int incl = v0;
        #pragma unroll
        for (int s = 1; s < 64; s <<= 1) {
            int o = __shfl_up(incl, s);
            if (lane >= s) incl += o;
        }
        pref[lane] = incl - v0;
        int tot0 = __shfl(incl, 63);
        int v1 = __popcll(masks[64 + lane]);
        int incl1 = v1;
        #pragma unroll
        for (int s = 1; s < 64; s <<= 1) {
            int o = __shfl_up(incl1, s);
            if (lane >= s) incl1 += o;
        }
        pref[64 + lane] = tot0 + incl1 - v1;
        if (lane == 63) nnS = tot0 + incl1;
    }
    __syncthreads();
    for (int w = wv; w < NPTS / 64; w += 16) {
        int i = w * 64 + lane;
        unsigned long long bm = masks[w];
        if ((bm >> lane) & 1ull) {
            int p = pref[w] + __popcll(bm & ((1ull << lane) - 1ull));
            if (p < NLCAP) {
                nlist_g[g * NLCAP + p] = i;
                const float* r = x + (size_t)i * XCOLS;
                float px = r[0], py = r[1], pz = r[2];
                qg[g * NLCAP + p] = make_float4(px, py, pz, px*px + py*py + pz*pz);
            }
        }
    }
    if (tid == 0) nn_g[g] = (nnS > NLCAP) ? NLCAP : nnS;
}

// ---------------- pairs: per-(group,slice) adjacency -> global edges + deg ---
// grid = 10*16; block 256 (4 waves). Wave w owns chunks c==w (mod 4); lane owns
// rows s + NSLICE*(lane + 64k), k<KRT. KRT=1 covers nn<=1024 (the real case:
// nn~820) -> no dead-row compute; KRT=2 fallback covers nn up to NLCAP with a
// live-row guard.
template<int KRT>
__device__ __forceinline__ void pairs_body(
        const float4* __restrict__ pts, int* __restrict__ srowdeg,
        unsigned int* __restrict__ eg, unsigned int* __restrict__ gcount,
        int nn, int s, int lane, int wq) {
    int rrow[KRT]; float4 qu[KRT]; int rowdeg[KRT];
    #pragma unroll
    for (int k = 0; k < KRT; k++) {
        int m = lane + 64 * k;
        int rr = s + NSLICE * m;
        bool live = rr < NLCAP;
        rrow[k] = live ? rr : 0;
        qu[k] = live ? pts[rrow[k]] : make_float4(0.f, 0.f, 0.f, 3.0e38f);
        rowdeg[k] = 0;
    }
    const int NC = (nn + 31) >> 5;
    for (int c = wq; c < NC; c += 4) {
        int base = c << 5;
        unsigned int bits[KRT];
        #pragma unroll
        for (int k = 0; k < KRT; k++) bits[k] = 0u;
        #pragma unroll
        for (int t = 0; t < 32; t++) {
            float4 qv = pts[base + t];               // wave-uniform broadcast
            #pragma unroll
            for (int k = 0; k < KRT; k++) {
                float d2 = qu[k].w + qv.w - 2.0f * (qu[k].x*qv.x + qu[k].y*qv.y + qu[k].z*qv.z);
                bits[k] |= (d2 < EPS2) ? (1u << t) : 0u;
            }
        }
        int cnt = 0;
        #pragma unroll
        for (int k = 0; k < KRT; k++) {
            int d = rrow[k] - base;                  // keep only v > u
            if (d >= 31) bits[k] = 0u;
            else if (d >= 0) bits[k] &= ~((2u << d) - 1u);
            int pc = __popc(bits[k]);
            rowdeg[k] += pc;
            cnt += pc;
        }
        int incl = cnt;
        #pragma unroll
        for (int st = 1; st < 64; st <<= 1) {
            int o = __shfl_up(incl, st);
            if (lane >= st) incl += o;
        }
        int tot = __shfl(incl, 63);
        if (tot > 0) {
            unsigned int rbase = 0;
            if (lane == 63) rbase = atomicAdd(gcount, (unsigned int)tot);
            rbase = __shfl(rbase, 63);
            unsigned int p = rbase + (unsigned int)(incl - cnt);
            #pragma unroll
            for (int k = 0; k < KRT; k++) {
                unsigned int b = bits[k];
                unsigned int uhi = (unsigned int)rrow[k] << 11;
                while (b) {
                    int t = __ffs(b) - 1; b &= b - 1;
                    if (p < EACAP) eg[p] = uhi | (unsigned int)(base + t);
                    p++;
                }
            }
        }
    }
    #pragma unroll
    for (int k = 0; k < KRT; k++)
        if (rowdeg[k] > 0) atomicAdd(&srowdeg[lane + 64 * k], rowdeg[k]);
}

__global__ void __launch_bounds__(256) k_pairs(
        const float4* __restrict__ qg, const int* __restrict__ nn_g,
        unsigned int* __restrict__ eAll_g, unsigned int* __restrict__ gcnt,
        int* __restrict__ deg_g) {
    __shared__ float4 pts[NLCAP];          // 24 KB
    __shared__ int srowdeg[NRPS];          // 96 rows this slice
    const int g = blockIdx.x / NSLICE;
    const int s = blockIdx.x % NSLICE;
    const int tid = threadIdx.x, lane = tid & 63, wq = tid >> 6;
    const int nn = nn_g[g];

    for (int k = tid; k < NLCAP; k += 256)           // coalesced packed copy
        pts[k] = (k < nn) ? qg[g * NLCAP + k]
                          : make_float4(0.f, 0.f, 0.f, 3.0e38f);
    for (int m = tid; m < NRPS; m += 256) srowdeg[m] = 0;
    __syncthreads();

    unsigned int* eg = eAll_g + (size_t)g * EACAP;
    if (nn <= 1024) pairs_body<1>(pts, srowdeg, eg, &gcnt[g * CPAD], nn, s, lane, wq);
    else            pairs_body<2>(pts, srowdeg, eg, &gcnt[g * CPAD], nn, s, lane, wq);
    __syncthreads();
    // this block is the unique owner of rows r==s (mod NSLICE): plain store
    for (int m = tid; m < NRPS; m += 256)
        deg_g[g * NLCAP + s + NSLICE * m] = 1 + srowdeg[m];  // +1 self-adjacency
}

// ---------------- graph: deg -> core -> SV -> rank -> border -> output -------
__global__ void __launch_bounds__(1024) k_graph(
        const unsigned int* __restrict__ eAll_g, const unsigned int* __restrict__ gcnt,
        const int* __restrict__ deg_g, const int* __restrict__ nlist_g,
        const int* __restrict__ nn_g, const float* __restrict__ x,
        float* __restrict__ out) {
    __shared__ unsigned int eA[EACAP];               // 32 KB
    __shared__ unsigned int eL[ELCAP];               // 32 KB
    __shared__ unsigned int eB[EBCAP];               // 8 KB
    __shared__ int sdeg[NLCAP];                      // 6 KB
    __shared__ int spar[NLCAP];                      // 6 KB
    __shared__ int scid[NLCAP];                      // 6 KB
    __shared__ int sbmin[NLCAP];                     // 6 KB
    __shared__ int nlist[NLCAP];                     // 6 KB
    __shared__ unsigned long long corebm[NLCAP/64];  // 192 B
    __shared__ unsigned long long repbm[NLCAP/64];   // 192 B
    __shared__ int nL, nB, sflag;

    const int g = blockIdx.x;
    const int tid = threadIdx.x, lane = tid & 63, wv = tid >> 6;
    const int NN = nn_g[g];
    unsigned int Eu = gcnt[g * CPAD];
    const int NA = (Eu > (unsigned)EACAP) ? EACAP : (int)Eu;

    if (tid == 0) { nL = 0; nB = 0; }
    for (int k = tid; k < NLCAP; k += 1024) {
        sdeg[k] = deg_g[g * NLCAP + k];
        spar[k] = k;
        sbmin[k] = BIGC;
        nlist[k] = nlist_g[g * NLCAP + k];
    }
    for (int e = tid; e < NA; e += 1024) eA[e] = eAll_g[(size_t)g * EACAP + e];
    __syncthreads();
    // v-side degrees
    for (int e = tid; e < NA; e += 1024) atomicAdd(&sdeg[eA[e] & 2047u], 1);
    __syncthreads();
    // core bitmap
    for (int w = wv; w < NLCAP / 64; w += 16) {
        int l = w * 64 + lane;
        bool isc = (l < NN) && (sdeg[l] >= MIN_PTS);
        unsigned long long bm = __ballot(isc);
        if (lane == 0) corebm[w] = bm;
    }
    __syncthreads();
    auto corebit = [&](int l) -> bool { return (corebm[l >> 6] >> (l & 63)) & 1ull; };

    // classify eA -> eL / eB (wave-aggregated)
    for (int e0 = 0; e0 < NA; e0 += 1024) {
        int e = e0 + tid;
        unsigned int pk = (e < NA) ? eA[e] : 0u;
        bool val = (e < NA);
        int u = (int)(pk >> 11), v = (int)(pk & 2047u);
        bool cu = val && corebit(u), cv = val && corebit(v);
        bool isL = cu && cv, isB = val && (cu != cv);
        unsigned long long mL = __ballot(isL);
        if (mL) {
            int b0 = 0;
            if (lane == 0) b0 = atomicAdd(&nL, __popcll(mL));
            b0 = __shfl(b0, 0);
            if (isL) {
                int idx = b0 + __popcll(mL & ((1ull << lane) - 1ull));
                if (idx < ELCAP) eL[idx] = pk;
            }
        }
        unsigned long long mB = __ballot(isB);
        if (mB) {
            int b0 = 0;
            if (lane == 0) b0 = atomicAdd(&nB, __popcll(mB));
            b0 = __shfl(b0, 0);
            if (isB) {
                int idx = b0 + __popcll(mB & ((1ull << lane) - 1ull));
                if (idx < EBCAP) eB[idx] = pk;
            }
        }
    }
    __syncthreads();
    const int NL = (nL > ELCAP) ? ELCAP : nL;
    const int NB = (nB > EBCAP) ? EBCAP : nB;

    // SV rounds: hook-to-min + DOUBLE pointer jump
    for (int r = 0; r < ROUNDS; r++) {
        if (tid == 0) sflag = 0;
        __syncthreads();
        for (int k = tid; k < NL; k += 1024) {
            unsigned int pk = eL[k];
            int u = (int)(pk >> 11), v = (int)(pk & 2047u);
            int a = spar[u], b2 = spar[v];
            if (a < b2)      { int old = atomicMin(&spar[v], a);  if (old > a)  sflag = 1; }
            else if (b2 < a) { int old = atomicMin(&spar[u], b2); if (old > b2) sflag = 1; }
        }
        __syncthreads();
        for (int k = tid; k < NN; k += 1024) {
            int s = spar[k]; int s2 = spar[s];
            if (s2 < s) { s = spar[s2]; spar[k] = (s < s2) ? s : s2; sflag = 1; }
        }
        __syncthreads();
        if (!sflag) break;
    }

    // reps + rank (wave 0 serial over 24 words)
    for (int w = wv; w < NLCAP / 64; w += 16) {
        int l = w * 64 + lane;
        bool isr = (l < NN) && corebit(l) && (spar[l] == l);
        unsigned long long bm = __ballot(isr);
        if (lane == 0) repbm[w] = bm;
    }
    __syncthreads();
    if (wv == 0) {
        int running = 0;
        for (int w = 0; w < NLCAP / 64; w++) {
            unsigned long long bm = repbm[w];
            if ((bm >> lane) & 1ull)
                scid[w * 64 + lane] = running + __popcll(bm & ((1ull << lane) - 1ull));
            running += __popcll(bm);
        }
    }
    __syncthreads();
    // ccid -> overwrite spar
    int cc[2];
    #pragma unroll
    for (int t = 0; t < 2; t++) {
        int k = tid + t * 1024;
        cc[t] = (k < NN && corebit(k)) ? scid[spar[k]] : BIGC;
    }
    __syncthreads();
    #pragma unroll
    for (int t = 0; t < 2; t++) {
        int k = tid + t * 1024;
        if (k < NN) spar[k] = cc[t];
    }
    __syncthreads();
    // border: min adjacent core cid for the non-core endpoint
    for (int k = tid; k < NB; k += 1024) {
        unsigned int pk = eB[k];
        int u = (int)(pk >> 11), v = (int)(pk & 2047u);
        int cu = spar[u], cv = spar[v];
        if (cu == BIGC) atomicMin(&sbmin[u], cv);
        else            atomicMin(&sbmin[v], cu);
    }
    __syncthreads();
    // final labels + clustered output
    for (int k = tid; k < NN; k += 1024) {
        int i = nlist[k];
        int c = spar[k];
        int lbl = (c != BIGC) ? c : ((sbmin[k] < BIGC) ? sbmin[k] : -1);
        out[i] = (float)lbl;
        const float* r = x + (size_t)i * XCOLS;
        float* o = out + NPTS + (size_t)i * 5;
        bool keep = lbl >= 0;
        #pragma unroll
        for (int c5 = 0; c5 < 5; c5++) o[c5] = keep ? r[c5] : 0.0f;
    }
}

extern "C" void kernel_launch(void* const* d_in, const int* in_sizes, int n_in,
                              void* d_out, int out_size, void* d_ws, size_t ws_size,
                              hipStream_t stream) {
    const float* x = (const float*)d_in[0];
    float* out = (float*)d_out;
    char* ws = (char*)d_ws;

    // workspace layout (~683 KB)
    float4* qg          = (float4*)(ws);                  // 10*1536*16 = 245760 B
    unsigned int* gcnt  = (unsigned int*)(ws + 245760);   // 10*64*4 = 2560
    int* nn_g           = (int*)(ws + 248320);            // 64
    int* nlist_g        = (int*)(ws + 248384);            // 10*1536*4 = 61440
    int* deg_g          = (int*)(ws + 309824);            // 61440
    unsigned int* eAll_g= (unsigned int*)(ws + 371264);   // 10*8192*4 = 327680

    k_prep<<<NGROUPS, 1024, 0, stream>>>(x, qg, nlist_g, nn_g, gcnt);
    k_pairs<<<NGROUPS * NSLICE, 256, 0, stream>>>(qg, nn_g, eAll_g, gcnt, deg_g);
    k_graph<<<NGROUPS, 1024, 0, stream>>>(eAll_g, gcnt, deg_g, nlist_g, nn_g, x, out);
}